// Round 7
// baseline (715.997 us; speedup 1.0000x reference)
//
#include <hip/hip_runtime.h>
#include <hip/hip_fp16.h>
#include <hip/hip_cooperative_groups.h>
#include <type_traits>

namespace cg = cooperative_groups;

// ---------------------------------------------------------------------------
// 2-layer GCN. Round 7:
//  - r6 lesson: aggregate time tracks past-L2 bytes (~2.1 TB/s random-access
//    ceiling), NOT instruction count. And ~95us of 298 is launch/drain gaps
//    across 13 dispatches.
//  - build_coop2: entire partition build (hist -> chunk scan -> bucket scan
//    -> scatter0 -> regroup_count -> regroup_scatter) in ONE cooperative
//    kernel with grid.sync() phase barriers (782 blocks, 3.2KB LDS ->
//    trivially co-resident; falls back to 6 separate kernels if the
//    cooperative launch errors).
//  - aggregate2: unroll-16 (8 x 256B gathers in flight per half-wave) as an
//    MLP probe; fp16 layer-1 activation (halves agg1 WRITE + gemm2 FETCH).
// Dispatches: 13 -> 5 (build, gemm1, agg1, gemm2, agg2).
// ---------------------------------------------------------------------------

#define D 64
#define NPB 128          // nodes per bucket (dst >> 7)
#define MAXB 784         // >= ceil(100000/128) = 782
#define CHUNK 8192       // edges per partition chunk

// ===========================================================================
// Cooperative single-dispatch build
// ===========================================================================
__global__ __launch_bounds__(256) void build_coop2(const int* __restrict__ src,
                                                   const int* __restrict__ dst,
                                                   int* __restrict__ counts,
                                                   int* __restrict__ btot,
                                                   int* __restrict__ bbase,
                                                   int* __restrict__ off,
                                                   int* __restrict__ deg,
                                                   float* __restrict__ dinv,
                                                   int* __restrict__ entries0,
                                                   int2* __restrict__ entries1,
                                                   int nE, int B, int C, int N) {
    cg::grid_group grid = cg::this_grid();
    __shared__ int sm[MAXB];
    const int t = threadIdx.x;

    // P0: per-chunk bucket histogram (LDS atomics only)
    for (int c = blockIdx.x; c < C; c += gridDim.x) {
        for (int b = t; b < B; b += 256) sm[b] = 0;
        __syncthreads();
        int e0 = c * CHUNK;
#pragma unroll
        for (int i = 0; i < CHUNK / 256; ++i) {
            int e = e0 + i * 256 + t;
            if (e < nE) atomicAdd(&sm[dst[e] >> 7], 1);
        }
        __syncthreads();
        for (int b = t; b < B; b += 256) counts[c * B + b] = sm[b];
        __syncthreads();
    }
    grid.sync();

    // P1: per-bucket exclusive scan over chunks (in-place), one wave/bucket
    for (int b = blockIdx.x * 4 + (t >> 6); b < B; b += gridDim.x * 4) {
        int lane = t & 63;
        int running = 0;
        for (int c0 = 0; c0 < C; c0 += 64) {
            int c = c0 + lane;
            int v = (c < C) ? counts[c * B + b] : 0;
            int x = v;
#pragma unroll
            for (int s = 1; s < 64; s <<= 1) {
                int u = __shfl_up(x, s);
                if (lane >= s) x += u;
            }
            if (c < C) counts[c * B + b] = running + x - v;
            running += __shfl(x, 63);
        }
        if (lane == 0) btot[b] = running;
    }
    grid.sync();

    // P2: bucket-total exclusive scan (block 0, 256 threads, B <= 1024)
    if (blockIdx.x == 0) {
        int i0 = t * 4;
        int a0 = (i0 + 0 < B) ? btot[i0 + 0] : 0;
        int a1 = (i0 + 1 < B) ? btot[i0 + 1] : 0;
        int a2 = (i0 + 2 < B) ? btot[i0 + 2] : 0;
        int a3 = (i0 + 3 < B) ? btot[i0 + 3] : 0;
        int l0 = a0, l1 = l0 + a1, l2 = l1 + a2, l3 = l2 + a3;
        sm[t] = l3;
        __syncthreads();
        for (int s = 1; s < 256; s <<= 1) {
            int u = (t >= s) ? sm[t - s] : 0;
            __syncthreads();
            sm[t] += u;
            __syncthreads();
        }
        int prefix = (t > 0) ? sm[t - 1] : 0;
        if (i0 + 0 < B) bbase[i0 + 0] = prefix;
        if (i0 + 1 < B) bbase[i0 + 1] = prefix + l0;
        if (i0 + 2 < B) bbase[i0 + 2] = prefix + l1;
        if (i0 + 3 < B) bbase[i0 + 3] = prefix + l2;
        if (t == 255) bbase[B] = sm[255];
    }
    grid.sync();

    // P3: scatter 4B entries (src | dloc<<17) via LDS cursors
    for (int c = blockIdx.x; c < C; c += gridDim.x) {
        for (int b = t; b < B; b += 256) sm[b] = counts[c * B + b] + bbase[b];
        __syncthreads();
        int e0 = c * CHUNK;
#pragma unroll
        for (int i = 0; i < CHUNK / 256; ++i) {
            int e = e0 + i * 256 + t;
            if (e < nE) {
                int s = src[e], d = dst[e];
                int pos = atomicAdd(&sm[d >> 7], 1);
                entries0[pos] = s | ((d & (NPB - 1)) << 17);
            }
        }
        __syncthreads();
    }
    grid.sync();

    // P4: per-bucket node counts -> off / deg / dinv
    for (int b = blockIdx.x; b < B; b += gridDim.x) {
        int* cnt = sm;          // [0,128)
        int* scn = sm + NPB;    // [128,256)
        if (t < NPB) cnt[t] = 0;
        __syncthreads();
        int s0 = bbase[b], s1 = bbase[b + 1];
        for (int p = s0 + t; p < s1; p += 256)
            atomicAdd(&cnt[(entries0[p] >> 17) & (NPB - 1)], 1);
        __syncthreads();
        if (t < NPB) scn[t] = cnt[t];
        __syncthreads();
        for (int s = 1; s < NPB; s <<= 1) {
            int u = 0;
            if (t < NPB && t >= s) u = scn[t - s];
            __syncthreads();
            if (t < NPB) scn[t] += u;
            __syncthreads();
        }
        if (t < NPB) {
            int node = b * NPB + t;
            if (node < N) {
                int c = cnt[t];
                off[node]  = s0 + scn[t] - c;
                deg[node]  = c;
                dinv[node] = rsqrtf((float)c + 1.0f);
            }
        }
        __syncthreads();
    }
    grid.sync();

    // P5: node-sorted {src, norm} entries
    for (int b = blockIdx.x; b < B; b += gridDim.x) {
        if (t < NPB) {
            int node = b * NPB + t;
            sm[t] = (node < N) ? off[node] : 0;
        }
        __syncthreads();
        int s0 = bbase[b], s1 = bbase[b + 1];
        for (int p = s0 + t; p < s1; p += 256) {
            int e = entries0[p];
            int s = e & 0x1FFFF;
            int dloc = (e >> 17) & (NPB - 1);
            int pos = atomicAdd(&sm[dloc], 1);
            float nrm = dinv[s] * dinv[b * NPB + dloc];
            entries1[pos] = make_int2(s, __float_as_int(nrm));
        }
        __syncthreads();
    }
}

// ===========================================================================
// Separate build kernels (fallback if cooperative launch errors)
// ===========================================================================
__global__ __launch_bounds__(256) void hist_kernel(const int* __restrict__ dst,
                                                   int* __restrict__ counts,
                                                   int nE, int B) {
    __shared__ int hist[MAXB];
    int c = blockIdx.x;
    for (int b = threadIdx.x; b < B; b += 256) hist[b] = 0;
    __syncthreads();
    int e0 = c * CHUNK;
#pragma unroll
    for (int i = 0; i < CHUNK / 256; ++i) {
        int e = e0 + i * 256 + threadIdx.x;
        if (e < nE) atomicAdd(&hist[dst[e] >> 7], 1);
    }
    __syncthreads();
    for (int b = threadIdx.x; b < B; b += 256) counts[c * B + b] = hist[b];
}

__global__ __launch_bounds__(256) void scan_chunks(int* __restrict__ counts,
                                                   int* __restrict__ bucketTotal,
                                                   int B, int C) {
    int b = blockIdx.x * 4 + (threadIdx.x >> 6);
    if (b >= B) return;
    int lane = threadIdx.x & 63;
    int running = 0;
    for (int c0 = 0; c0 < C; c0 += 64) {
        int c = c0 + lane;
        int v = (c < C) ? counts[c * B + b] : 0;
        int x = v;
#pragma unroll
        for (int s = 1; s < 64; s <<= 1) {
            int u = __shfl_up(x, s);
            if (lane >= s) x += u;
        }
        if (c < C) counts[c * B + b] = running + x - v;
        running += __shfl(x, 63);
    }
    if (lane == 0) bucketTotal[b] = running;
}

__global__ __launch_bounds__(1024) void scan_buckets(const int* __restrict__ bucketTotal,
                                                     int* __restrict__ bucketBase, int B) {
    __shared__ int sdata[1024];
    int t = threadIdx.x;
    int v = (t < B) ? bucketTotal[t] : 0;
    sdata[t] = v;
    __syncthreads();
    for (int s = 1; s < 1024; s <<= 1) {
        int u = (t >= s) ? sdata[t - s] : 0;
        __syncthreads();
        sdata[t] += u;
        __syncthreads();
    }
    if (t < B) bucketBase[t] = sdata[t] - v;
    if (t == B - 1) bucketBase[B] = sdata[t];
}

__global__ __launch_bounds__(256) void scatter0_kernel(const int* __restrict__ src,
                                                       const int* __restrict__ dst,
                                                       const int* __restrict__ base,
                                                       const int* __restrict__ bbase,
                                                       int* __restrict__ entries0,
                                                       int nE, int B) {
    __shared__ int cur[MAXB];
    int c = blockIdx.x;
    for (int b = threadIdx.x; b < B; b += 256) cur[b] = base[c * B + b] + bbase[b];
    __syncthreads();
    int e0 = c * CHUNK;
#pragma unroll
    for (int i = 0; i < CHUNK / 256; ++i) {
        int e = e0 + i * 256 + threadIdx.x;
        if (e < nE) {
            int s = src[e], d = dst[e];
            int pos = atomicAdd(&cur[d >> 7], 1);
            entries0[pos] = s | ((d & (NPB - 1)) << 17);
        }
    }
}

__global__ __launch_bounds__(256) void regroup_count(const int* __restrict__ entries0,
                                                     const int* __restrict__ bbase,
                                                     int* __restrict__ off,
                                                     int* __restrict__ deg,
                                                     float* __restrict__ dinv, int N) {
    __shared__ int cnt[NPB];
    __shared__ int scn[NPB];
    int b = blockIdx.x;
    int t = threadIdx.x;
    if (t < NPB) cnt[t] = 0;
    __syncthreads();
    int s0 = bbase[b], s1 = bbase[b + 1];
    for (int p = s0 + t; p < s1; p += 256)
        atomicAdd(&cnt[(entries0[p] >> 17) & (NPB - 1)], 1);
    __syncthreads();
    if (t < NPB) scn[t] = cnt[t];
    __syncthreads();
    for (int s = 1; s < NPB; s <<= 1) {
        int u = 0;
        if (t < NPB && t >= s) u = scn[t - s];
        __syncthreads();
        if (t < NPB) scn[t] += u;
        __syncthreads();
    }
    if (t < NPB) {
        int node = b * NPB + t;
        if (node < N) {
            int c = cnt[t];
            off[node]  = s0 + scn[t] - c;
            deg[node]  = c;
            dinv[node] = rsqrtf((float)c + 1.0f);
        }
    }
}

__global__ __launch_bounds__(256) void regroup_scatter(const int* __restrict__ entries0,
                                                       const int* __restrict__ bbase,
                                                       const int* __restrict__ off,
                                                       const float* __restrict__ dinv,
                                                       int2* __restrict__ entries1, int N) {
    __shared__ int cur[NPB];
    int b = blockIdx.x;
    int t = threadIdx.x;
    if (t < NPB) {
        int node = b * NPB + t;
        cur[t] = (node < N) ? off[node] : 0;
    }
    __syncthreads();
    int s0 = bbase[b], s1 = bbase[b + 1];
    for (int p = s0 + t; p < s1; p += 256) {
        int e = entries0[p];
        int s = e & 0x1FFFF;
        int dloc = (e >> 17) & (NPB - 1);
        int pos = atomicAdd(&cur[dloc], 1);
        float nrm = dinv[s] * dinv[b * NPB + dloc];
        entries1[pos] = make_int2(s, __float_as_int(nrm));
    }
}

// ===========================================================================
// aggregate2: one wave per node, dual-edge half2 layout, unroll-16
// ===========================================================================
template <typename OutT>
__global__ __launch_bounds__(256) void aggregate2(const int2* __restrict__ csr,
                                                  const int* __restrict__ off,
                                                  const int* __restrict__ deg,
                                                  const float* __restrict__ dinv,
                                                  const __half* __restrict__ H,
                                                  const float* __restrict__ bias,
                                                  OutT* __restrict__ out, int N) {
    int node = blockIdx.x * 4 + (threadIdx.x >> 6);
    if (node >= N) return;
    int lane = threadIdx.x & 63;
    int p2 = lane & 31;
    int h  = lane >> 5;
    const __half2* H2 = (const __half2*)H;
    float2 acc = make_float2(0.0f, 0.0f);
    int beg = off[node];
    int end = beg + deg[node];
    int p = beg;
    for (; p + 16 <= end; p += 16) {       // 8 x 256B gathers in flight
        int2 e[8];
#pragma unroll
        for (int i = 0; i < 8; ++i) e[i] = csr[p + 2 * i + h];
        __half2 g[8];
#pragma unroll
        for (int i = 0; i < 8; ++i) g[i] = H2[(size_t)e[i].x * 32 + p2];
#pragma unroll
        for (int i = 0; i < 8; ++i) {
            float2 f = __half22float2(g[i]);
            float c = __int_as_float(e[i].y);
            acc.x += f.x * c; acc.y += f.y * c;
        }
    }
    for (; p + 8 <= end; p += 8) {
        int2 e0 = csr[p + 0 + h], e1 = csr[p + 2 + h];
        int2 e2 = csr[p + 4 + h], e3 = csr[p + 6 + h];
        __half2 g0 = H2[(size_t)e0.x * 32 + p2];
        __half2 g1 = H2[(size_t)e1.x * 32 + p2];
        __half2 g2 = H2[(size_t)e2.x * 32 + p2];
        __half2 g3 = H2[(size_t)e3.x * 32 + p2];
        float2 f0 = __half22float2(g0), f1 = __half22float2(g1);
        float2 f2 = __half22float2(g2), f3 = __half22float2(g3);
        acc.x += f0.x * __int_as_float(e0.y); acc.y += f0.y * __int_as_float(e0.y);
        acc.x += f1.x * __int_as_float(e1.y); acc.y += f1.y * __int_as_float(e1.y);
        acc.x += f2.x * __int_as_float(e2.y); acc.y += f2.y * __int_as_float(e2.y);
        acc.x += f3.x * __int_as_float(e3.y); acc.y += f3.y * __int_as_float(e3.y);
    }
    for (; p + 2 <= end; p += 2) {
        int2 e0 = csr[p + h];
        __half2 g0 = H2[(size_t)e0.x * 32 + p2];
        float2 f0 = __half22float2(g0);
        float c0 = __int_as_float(e0.y);
        acc.x += f0.x * c0; acc.y += f0.y * c0;
    }
    if (p < end && h == 0) {
        int2 e0 = csr[p];
        __half2 g0 = H2[(size_t)e0.x * 32 + p2];
        float2 f0 = __half22float2(g0);
        float c0 = __int_as_float(e0.y);
        acc.x += f0.x * c0; acc.y += f0.y * c0;
    }
    acc.x += __shfl_xor(acc.x, 32);
    acc.y += __shfl_xor(acc.y, 32);
    if (h == 0) {
        float dd = dinv[node];
        float s = dd * dd;
        float2 hs = __half22float2(H2[(size_t)node * 32 + p2]);
        float2 bv = ((const float2*)bias)[p2];
        float2 o;
        o.x = acc.x + bv.x + hs.x * s;
        o.y = acc.y + bv.y + hs.y * s;
        if constexpr (sizeof(OutT) == 2) {
            ((__half2*)(out + (size_t)node * D))[p2] = __float22half2_rn(o);
        } else {
            ((float2*)(out + (size_t)node * D))[p2] = o;
        }
    }
}

// ===========================================================================
// H(fp16) = X @ W^T : 64x64 block tile, 4x4 register tile. X fp32 or fp16.
// ===========================================================================
template <typename InT>
__global__ __launch_bounds__(256) void gemm_xwt_h(const InT* __restrict__ X,
                                                  const float* __restrict__ W,
                                                  __half* __restrict__ H, int N) {
    __shared__ float xt[64 * 68];
    __shared__ float wt[64 * 68];
    const int t = threadIdx.x;
    const int i0 = blockIdx.x * 64;
#pragma unroll
    for (int r = 0; r < 16; ++r) {
        int idx = r * 256 + t;
        int j = idx >> 6, k = idx & 63;
        wt[k * 68 + j] = W[idx];
    }
#pragma unroll
    for (int r = 0; r < 16; ++r) {
        int idx = r * 256 + t;
        int i = idx >> 6, k = idx & 63;
        float v = 0.0f;
        if (i0 + i < N) {
            if constexpr (sizeof(InT) == 2)
                v = __half2float(((const __half*)X)[(size_t)(i0 + i) * D + k]);
            else
                v = ((const float*)X)[(size_t)(i0 + i) * D + k];
        }
        xt[k * 68 + i] = v;
    }
    __syncthreads();
    const int tn = (t & 15) * 4;
    const int tc = (t >> 4) * 4;
    float acc[4][4] = {};
#pragma unroll 8
    for (int k = 0; k < 64; ++k) {
        const float4 xa = *(const float4*)(xt + k * 68 + tn);
        const float4 wb = *(const float4*)(wt + k * 68 + tc);
        acc[0][0] += xa.x * wb.x; acc[0][1] += xa.x * wb.y; acc[0][2] += xa.x * wb.z; acc[0][3] += xa.x * wb.w;
        acc[1][0] += xa.y * wb.x; acc[1][1] += xa.y * wb.y; acc[1][2] += xa.y * wb.z; acc[1][3] += xa.y * wb.w;
        acc[2][0] += xa.z * wb.x; acc[2][1] += xa.z * wb.y; acc[2][2] += xa.z * wb.z; acc[2][3] += xa.z * wb.w;
        acc[3][0] += xa.w * wb.x; acc[3][1] += xa.w * wb.y; acc[3][2] += xa.w * wb.z; acc[3][3] += xa.w * wb.w;
    }
#pragma unroll
    for (int a = 0; a < 4; ++a) {
        int i = i0 + tn + a;
        if (i < N) {
            union { __half2 h2[2]; uint2 u2; } pk;
            pk.h2[0].x = __float2half_rn(acc[a][0]);
            pk.h2[0].y = __float2half_rn(acc[a][1]);
            pk.h2[1].x = __float2half_rn(acc[a][2]);
            pk.h2[1].y = __float2half_rn(acc[a][3]);
            *(uint2*)(&H[(size_t)i * D + tc]) = pk.u2;
        }
    }
}

// ===========================================================================
// Ultimate fallback (round-1 fp32 atomic path) kernels
// ===========================================================================
__global__ __launch_bounds__(256) void deg_kernel(const int* __restrict__ dst,
                                                  int* __restrict__ deg, int nE) {
    int e = blockIdx.x * 256 + threadIdx.x;
    if (e < nE) atomicAdd(&deg[dst[e]], 1);
}

__global__ __launch_bounds__(256) void dinv_kernel(const int* __restrict__ deg,
                                                   float* __restrict__ dinv, int N) {
    int i = blockIdx.x * 256 + threadIdx.x;
    if (i < N) dinv[i] = rsqrtf((float)deg[i] + 1.0f);
}

__global__ __launch_bounds__(256) void gemm_xwt(const float* __restrict__ X,
                                                const float* __restrict__ W,
                                                float* __restrict__ H, int N) {
    __shared__ float xt[64 * 68];
    __shared__ float wt[64 * 68];
    const int t = threadIdx.x;
    const int i0 = blockIdx.x * 64;
#pragma unroll
    for (int r = 0; r < 16; ++r) {
        int idx = r * 256 + t;
        int j = idx >> 6, k = idx & 63;
        wt[k * 68 + j] = W[idx];
    }
#pragma unroll
    for (int r = 0; r < 16; ++r) {
        int idx = r * 256 + t;
        int i = idx >> 6, k = idx & 63;
        float v = 0.0f;
        if (i0 + i < N) v = X[(size_t)(i0 + i) * D + k];
        xt[k * 68 + i] = v;
    }
    __syncthreads();
    const int tn = (t & 15) * 4;
    const int tc = (t >> 4) * 4;
    float acc[4][4] = {};
#pragma unroll 8
    for (int k = 0; k < 64; ++k) {
        const float4 xa = *(const float4*)(xt + k * 68 + tn);
        const float4 wb = *(const float4*)(wt + k * 68 + tc);
        acc[0][0] += xa.x * wb.x; acc[0][1] += xa.x * wb.y; acc[0][2] += xa.x * wb.z; acc[0][3] += xa.x * wb.w;
        acc[1][0] += xa.y * wb.x; acc[1][1] += xa.y * wb.y; acc[1][2] += xa.y * wb.z; acc[1][3] += xa.y * wb.w;
        acc[2][0] += xa.z * wb.x; acc[2][1] += xa.z * wb.y; acc[2][2] += xa.z * wb.z; acc[2][3] += xa.z * wb.w;
        acc[3][0] += xa.w * wb.x; acc[3][1] += xa.w * wb.y; acc[3][2] += xa.w * wb.z; acc[3][3] += xa.w * wb.w;
    }
#pragma unroll
    for (int a = 0; a < 4; ++a) {
        int i = i0 + tn + a;
        if (i < N) {
            float4 o = make_float4(acc[a][0], acc[a][1], acc[a][2], acc[a][3]);
            *(float4*)(H + (size_t)i * D + tc) = o;
        }
    }
}

__global__ __launch_bounds__(256) void init_out(const float* __restrict__ H,
                                                const float* __restrict__ dinv,
                                                const float* __restrict__ b,
                                                float* __restrict__ out, int N) {
    int idx4 = blockIdx.x * 256 + threadIdx.x;
    if (idx4 >= N * 16) return;
    int i = idx4 >> 4;
    int jc = idx4 & 15;
    float di = dinv[i];
    float s = di * di;
    float4 h4 = ((const float4*)H)[idx4];
    float4 b4 = ((const float4*)b)[jc];
    ((float4*)out)[idx4] = make_float4(b4.x + h4.x * s, b4.y + h4.y * s,
                                       b4.z + h4.z * s, b4.w + h4.w * s);
}

__global__ __launch_bounds__(256) void edge_scatter(const int* __restrict__ src,
                                                    const int* __restrict__ dst,
                                                    const float* __restrict__ dinv,
                                                    const float* __restrict__ H,
                                                    float* __restrict__ out, int nE) {
    int tid = blockIdx.x * 256 + threadIdx.x;
    int e = tid >> 4;
    if (e >= nE) return;
    int l = tid & 15;
    int s = src[e];
    int d = dst[e];
    float c = dinv[s] * dinv[d];
    float4 v = ((const float4*)H)[s * 16 + l];
    float* o = out + (size_t)d * D + l * 4;
    unsafeAtomicAdd(o + 0, v.x * c);
    unsafeAtomicAdd(o + 1, v.y * c);
    unsafeAtomicAdd(o + 2, v.z * c);
    unsafeAtomicAdd(o + 3, v.w * c);
}

static inline size_t align_up(size_t v, size_t a) { return (v + a - 1) & ~(a - 1); }

extern "C" void kernel_launch(void* const* d_in, const int* in_sizes, int n_in,
                              void* d_out, int out_size, void* d_ws, size_t ws_size,
                              hipStream_t stream) {
    const float* x  = (const float*)d_in[0];
    const int*   ei = (const int*)d_in[1];
    const float* W1 = (const float*)d_in[2];
    const float* b1 = (const float*)d_in[3];
    const float* W2 = (const float*)d_in[4];
    const float* b2 = (const float*)d_in[5];
    float* out = (float*)d_out;

    const int N  = in_sizes[0] / D;   // 100000
    const int nE = in_sizes[1] / 2;   // 1600000
    const int* srcp = ei;
    const int* dstv = ei + nE;

    const int B = (N + NPB - 1) / NPB;      // 782
    const int C = (nE + CHUNK - 1) / CHUNK; // 196

    // --- workspace layout (bump allocator, 256B aligned) ---
    char* base_p = (char*)d_ws;
    size_t o = 0;
    int* counts = (int*)(base_p + o);  o = align_up(o + (size_t)C * B * 4, 256);
    int* btot   = (int*)(base_p + o);  o = align_up(o + (size_t)B * 4, 256);
    int* bbase  = (int*)(base_p + o);  o = align_up(o + (size_t)(B + 1) * 4, 256);
    int* off    = (int*)(base_p + o);  o = align_up(o + (size_t)N * 4, 256);
    int* deg    = (int*)(base_p + o);  o = align_up(o + (size_t)N * 4, 256);
    float* dinv = (float*)(base_p + o); o = align_up(o + (size_t)N * 4, 256);
    int2* entries1 = (int2*)(base_p + o); o = align_up(o + (size_t)nE * 8, 256);
    // region2: entries0 (nE*4) while building; Hh (N*D*2) afterwards
    size_t r2 = (size_t)nE * 4 > (size_t)N * D * 2 ? (size_t)nE * 4 : (size_t)N * D * 2;
    int* entries0 = (int*)(base_p + o);
    __half* Hh    = (__half*)(base_p + o);
    o = align_up(o + r2, 256);
    size_t need_base = o;              // ~28 MB
    __half* A1h = (__half*)(base_p + o);
    size_t need_full = o + align_up((size_t)N * D * 2, 256);  // ~41 MB

    int gb_n = (N + 255) / 256;
    int gb_g = (N + 63) / 64;
    int gb_e = (nE + 255) / 256;

    if (ws_size >= need_base && B <= MAXB && B <= 1024) {
        // ---- partition build: 1 cooperative dispatch (fallback: 6) ----
        int GB = B;
        int nE_ = nE, B_ = B, C_ = C, N_ = N;
        const int* src_ = srcp; const int* dst_ = dstv;
        int* counts_ = counts; int* btot_ = btot; int* bbase_ = bbase;
        int* off_ = off; int* deg_ = deg; float* dinv_ = dinv;
        int* e0_ = entries0; int2* e1_ = entries1;
        void* kargs[] = {&src_, &dst_, &counts_, &btot_, &bbase_, &off_, &deg_,
                         &dinv_, &e0_, &e1_, &nE_, &B_, &C_, &N_};
        hipError_t cerr = hipLaunchCooperativeKernel((const void*)build_coop2,
                                                     dim3(GB), dim3(256),
                                                     kargs, 0, stream);
        if (cerr != hipSuccess) {
            hist_kernel<<<C, 256, 0, stream>>>(dstv, counts, nE, B);
            scan_chunks<<<(B + 3) / 4, 256, 0, stream>>>(counts, btot, B, C);
            scan_buckets<<<1, 1024, 0, stream>>>(btot, bbase, B);
            scatter0_kernel<<<C, 256, 0, stream>>>(srcp, dstv, counts, bbase, entries0, nE, B);
            regroup_count<<<B, 256, 0, stream>>>(entries0, bbase, off, deg, dinv, N);
            regroup_scatter<<<B, 256, 0, stream>>>(entries0, bbase, off, dinv, entries1, N);
        }

        int gb_a = (N + 3) / 4;
        gemm_xwt_h<float><<<gb_g, 256, 0, stream>>>(x, W1, Hh, N);
        if (ws_size >= need_full) {
            aggregate2<__half><<<gb_a, 256, 0, stream>>>(entries1, off, deg, dinv, Hh, b1, A1h, N);
            gemm_xwt_h<__half><<<gb_g, 256, 0, stream>>>(A1h, W2, Hh, N);
        } else {
            aggregate2<float><<<gb_a, 256, 0, stream>>>(entries1, off, deg, dinv, Hh, b1, out, N);
            gemm_xwt_h<float><<<gb_g, 256, 0, stream>>>(out, W2, Hh, N);
        }
        aggregate2<float><<<gb_a, 256, 0, stream>>>(entries1, off, deg, dinv, Hh, b2, out, N);
    } else {
        // ---------------- fallback: round-1 atomic path ----------------
        size_t fo = 0;
        int* fdeg    = (int*)(base_p + fo);  fo = align_up(fo + (size_t)N * 4, 256);
        float* fdinv = (float*)(base_p + fo); fo = align_up(fo + (size_t)N * 4, 256);
        float* bufA  = (float*)(base_p + fo);
        hipMemsetAsync(fdeg, 0, (size_t)N * 4, stream);
        deg_kernel<<<gb_e, 256, 0, stream>>>(dstv, fdeg, nE);
        dinv_kernel<<<gb_n, 256, 0, stream>>>(fdeg, fdinv, N);
        int gb_i = (N * 16 + 255) / 256;
        int gb_e16 = (int)(((long long)nE * 16 + 255) / 256);
        gemm_xwt<<<gb_g, 256, 0, stream>>>(x, W1, bufA, N);
        init_out<<<gb_i, 256, 0, stream>>>(bufA, fdinv, b1, out, N);
        edge_scatter<<<gb_e16, 256, 0, stream>>>(srcp, dstv, fdinv, bufA, out, nE);
        gemm_xwt<<<gb_g, 256, 0, stream>>>(out, W2, bufA, N);
        init_out<<<gb_i, 256, 0, stream>>>(bufA, fdinv, b2, out, N);
        edge_scatter<<<gb_e16, 256, 0, stream>>>(srcp, dstv, fdinv, bufA, out, nE);
    }
}

// Round 8
// 299.899 us; speedup vs baseline: 2.3875x; 2.3875x over previous
//
#include <hip/hip_runtime.h>
#include <hip/hip_fp16.h>

// ---------------------------------------------------------------------------
// 2-layer GCN. Round 8: REVERT cooperative build (grid.sync costs ~90us/sync
// on ROCm/gfx950 -> 470us for the build; separate kernels do it in ~55us).
// Keep r6's proven pipeline + r7's incremental wins:
//  - aggregate2 unroll-16 (8 x 256B gathers in flight per half-wave)
//  - fp16 layer-1 activation (halves agg1 write + gemm2 fetch)
//  - in-place chunk scan (no cbase buffer), 256-thread bucket scan
// Dispatch list: hist, scan_chunks, scan_buckets, scatter0, regroup_count,
// regroup_scatter, gemm1, agg1, gemm2, agg2  (10 dispatches).
// ---------------------------------------------------------------------------

#define D 64
#define NPB 128          // nodes per bucket (dst >> 7)
#define MAXB 784         // >= ceil(100000/128) = 782
#define CHUNK 8192       // edges per partition chunk

// --- A1: per-chunk bucket histogram (LDS atomics only) ---------------------
__global__ __launch_bounds__(256) void hist_kernel(const int* __restrict__ dst,
                                                   int* __restrict__ counts,
                                                   int nE, int B) {
    __shared__ int hist[MAXB];
    int c = blockIdx.x;
    for (int b = threadIdx.x; b < B; b += 256) hist[b] = 0;
    __syncthreads();
    int e0 = c * CHUNK;
#pragma unroll
    for (int i = 0; i < CHUNK / 256; ++i) {
        int e = e0 + i * 256 + threadIdx.x;
        if (e < nE) atomicAdd(&hist[dst[e] >> 7], 1);
    }
    __syncthreads();
    for (int b = threadIdx.x; b < B; b += 256) counts[c * B + b] = hist[b];
}

// --- S1: per-bucket exclusive scan over chunks, IN PLACE (1 wave/bucket) ---
__global__ __launch_bounds__(256) void scan_chunks(int* __restrict__ counts,
                                                   int* __restrict__ bucketTotal,
                                                   int B, int C) {
    int b = blockIdx.x * 4 + (threadIdx.x >> 6);
    if (b >= B) return;
    int lane = threadIdx.x & 63;
    int running = 0;
    for (int c0 = 0; c0 < C; c0 += 64) {
        int c = c0 + lane;
        int v = (c < C) ? counts[c * B + b] : 0;
        int x = v;
#pragma unroll
        for (int s = 1; s < 64; s <<= 1) {
            int u = __shfl_up(x, s);
            if (lane >= s) x += u;
        }
        if (c < C) counts[c * B + b] = running + x - v;
        running += __shfl(x, 63);
    }
    if (lane == 0) bucketTotal[b] = running;
}

// --- S2: bucket-total exclusive scan (256 threads, 4 items/thread) ---------
__global__ __launch_bounds__(256) void scan_buckets(const int* __restrict__ btot,
                                                    int* __restrict__ bbase, int B) {
    __shared__ int sm[256];
    int t = threadIdx.x;
    int i0 = t * 4;
    int a0 = (i0 + 0 < B) ? btot[i0 + 0] : 0;
    int a1 = (i0 + 1 < B) ? btot[i0 + 1] : 0;
    int a2 = (i0 + 2 < B) ? btot[i0 + 2] : 0;
    int a3 = (i0 + 3 < B) ? btot[i0 + 3] : 0;
    int l0 = a0, l1 = l0 + a1, l2 = l1 + a2, l3 = l2 + a3;
    sm[t] = l3;
    __syncthreads();
    for (int s = 1; s < 256; s <<= 1) {
        int u = (t >= s) ? sm[t - s] : 0;
        __syncthreads();
        sm[t] += u;
        __syncthreads();
    }
    int prefix = (t > 0) ? sm[t - 1] : 0;
    if (i0 + 0 < B) bbase[i0 + 0] = prefix;
    if (i0 + 1 < B) bbase[i0 + 1] = prefix + l0;
    if (i0 + 2 < B) bbase[i0 + 2] = prefix + l1;
    if (i0 + 3 < B) bbase[i0 + 3] = prefix + l2;
    if (t == 255) bbase[B] = sm[255];
}

// --- A3: scatter 4B entries (src | dloc<<17) via LDS cursors ---------------
__global__ __launch_bounds__(256) void scatter0_kernel(const int* __restrict__ src,
                                                       const int* __restrict__ dst,
                                                       const int* __restrict__ base,
                                                       const int* __restrict__ bbase,
                                                       int* __restrict__ entries0,
                                                       int nE, int B) {
    __shared__ int cur[MAXB];
    int c = blockIdx.x;
    for (int b = threadIdx.x; b < B; b += 256) cur[b] = base[c * B + b] + bbase[b];
    __syncthreads();
    int e0 = c * CHUNK;
#pragma unroll
    for (int i = 0; i < CHUNK / 256; ++i) {
        int e = e0 + i * 256 + threadIdx.x;
        if (e < nE) {
            int s = src[e], d = dst[e];
            int pos = atomicAdd(&cur[d >> 7], 1);
            entries0[pos] = s | ((d & (NPB - 1)) << 17);
        }
    }
}

// --- A4: per-bucket node counts -> off / deg / dinv ------------------------
__global__ __launch_bounds__(256) void regroup_count(const int* __restrict__ entries0,
                                                     const int* __restrict__ bbase,
                                                     int* __restrict__ off,
                                                     int* __restrict__ deg,
                                                     float* __restrict__ dinv, int N) {
    __shared__ int cnt[NPB];
    __shared__ int scn[NPB];
    int b = blockIdx.x;
    int t = threadIdx.x;
    if (t < NPB) cnt[t] = 0;
    __syncthreads();
    int s0 = bbase[b], s1 = bbase[b + 1];
    for (int p = s0 + t; p < s1; p += 256)
        atomicAdd(&cnt[(entries0[p] >> 17) & (NPB - 1)], 1);
    __syncthreads();
    if (t < NPB) scn[t] = cnt[t];
    __syncthreads();
    for (int s = 1; s < NPB; s <<= 1) {
        int u = 0;
        if (t < NPB && t >= s) u = scn[t - s];
        __syncthreads();
        if (t < NPB) scn[t] += u;
        __syncthreads();
    }
    if (t < NPB) {
        int node = b * NPB + t;
        if (node < N) {
            int c = cnt[t];
            off[node]  = s0 + scn[t] - c;
            deg[node]  = c;
            dinv[node] = rsqrtf((float)c + 1.0f);
        }
    }
}

// --- A5: node-sorted {src, norm}; writes within 16KB/bucket ----------------
__global__ __launch_bounds__(256) void regroup_scatter(const int* __restrict__ entries0,
                                                       const int* __restrict__ bbase,
                                                       const int* __restrict__ off,
                                                       const float* __restrict__ dinv,
                                                       int2* __restrict__ entries1, int N) {
    __shared__ int cur[NPB];
    int b = blockIdx.x;
    int t = threadIdx.x;
    if (t < NPB) {
        int node = b * NPB + t;
        cur[t] = (node < N) ? off[node] : 0;
    }
    __syncthreads();
    int s0 = bbase[b], s1 = bbase[b + 1];
    for (int p = s0 + t; p < s1; p += 256) {
        int e = entries0[p];
        int s = e & 0x1FFFF;
        int dloc = (e >> 17) & (NPB - 1);
        int pos = atomicAdd(&cur[dloc], 1);
        float nrm = dinv[s] * dinv[b * NPB + dloc];
        entries1[pos] = make_int2(s, __float_as_int(nrm));
    }
}

// --- aggregate2: one wave per node, dual-edge half2 layout, unroll-16 ------
template <typename OutT>
__global__ __launch_bounds__(256) void aggregate2(const int2* __restrict__ csr,
                                                  const int* __restrict__ off,
                                                  const int* __restrict__ deg,
                                                  const float* __restrict__ dinv,
                                                  const __half* __restrict__ H,
                                                  const float* __restrict__ bias,
                                                  OutT* __restrict__ out, int N) {
    int node = blockIdx.x * 4 + (threadIdx.x >> 6);
    if (node >= N) return;
    int lane = threadIdx.x & 63;
    int p2 = lane & 31;
    int h  = lane >> 5;
    const __half2* H2 = (const __half2*)H;
    float2 acc = make_float2(0.0f, 0.0f);
    int beg = off[node];
    int end = beg + deg[node];
    int p = beg;
    for (; p + 16 <= end; p += 16) {       // 8 x 256B gathers in flight
        int2 e[8];
#pragma unroll
        for (int i = 0; i < 8; ++i) e[i] = csr[p + 2 * i + h];
        __half2 g[8];
#pragma unroll
        for (int i = 0; i < 8; ++i) g[i] = H2[(size_t)e[i].x * 32 + p2];
#pragma unroll
        for (int i = 0; i < 8; ++i) {
            float2 f = __half22float2(g[i]);
            float c = __int_as_float(e[i].y);
            acc.x += f.x * c; acc.y += f.y * c;
        }
    }
    for (; p + 8 <= end; p += 8) {
        int2 e0 = csr[p + 0 + h], e1 = csr[p + 2 + h];
        int2 e2 = csr[p + 4 + h], e3 = csr[p + 6 + h];
        __half2 g0 = H2[(size_t)e0.x * 32 + p2];
        __half2 g1 = H2[(size_t)e1.x * 32 + p2];
        __half2 g2 = H2[(size_t)e2.x * 32 + p2];
        __half2 g3 = H2[(size_t)e3.x * 32 + p2];
        float2 f0 = __half22float2(g0), f1 = __half22float2(g1);
        float2 f2 = __half22float2(g2), f3 = __half22float2(g3);
        acc.x += f0.x * __int_as_float(e0.y); acc.y += f0.y * __int_as_float(e0.y);
        acc.x += f1.x * __int_as_float(e1.y); acc.y += f1.y * __int_as_float(e1.y);
        acc.x += f2.x * __int_as_float(e2.y); acc.y += f2.y * __int_as_float(e2.y);
        acc.x += f3.x * __int_as_float(e3.y); acc.y += f3.y * __int_as_float(e3.y);
    }
    for (; p + 2 <= end; p += 2) {
        int2 e0 = csr[p + h];
        __half2 g0 = H2[(size_t)e0.x * 32 + p2];
        float2 f0 = __half22float2(g0);
        float c0 = __int_as_float(e0.y);
        acc.x += f0.x * c0; acc.y += f0.y * c0;
    }
    if (p < end && h == 0) {
        int2 e0 = csr[p];
        __half2 g0 = H2[(size_t)e0.x * 32 + p2];
        float2 f0 = __half22float2(g0);
        float c0 = __int_as_float(e0.y);
        acc.x += f0.x * c0; acc.y += f0.y * c0;
    }
    acc.x += __shfl_xor(acc.x, 32);
    acc.y += __shfl_xor(acc.y, 32);
    if (h == 0) {
        float dd = dinv[node];
        float s = dd * dd;
        float2 hs = __half22float2(H2[(size_t)node * 32 + p2]);
        float2 bv = ((const float2*)bias)[p2];
        float2 o;
        o.x = acc.x + bv.x + hs.x * s;
        o.y = acc.y + bv.y + hs.y * s;
        if constexpr (sizeof(OutT) == 2) {
            ((__half2*)(out + (size_t)node * D))[p2] = __float22half2_rn(o);
        } else {
            ((float2*)(out + (size_t)node * D))[p2] = o;
        }
    }
}

// --- H(fp16) = X @ W^T : 64x64 block tile, 4x4 register tile ---------------
template <typename InT>
__global__ __launch_bounds__(256) void gemm_xwt_h(const InT* __restrict__ X,
                                                  const float* __restrict__ W,
                                                  __half* __restrict__ H, int N) {
    __shared__ float xt[64 * 68];
    __shared__ float wt[64 * 68];
    const int t = threadIdx.x;
    const int i0 = blockIdx.x * 64;
#pragma unroll
    for (int r = 0; r < 16; ++r) {
        int idx = r * 256 + t;
        int j = idx >> 6, k = idx & 63;
        wt[k * 68 + j] = W[idx];
    }
#pragma unroll
    for (int r = 0; r < 16; ++r) {
        int idx = r * 256 + t;
        int i = idx >> 6, k = idx & 63;
        float v = 0.0f;
        if (i0 + i < N) {
            if constexpr (sizeof(InT) == 2)
                v = __half2float(((const __half*)X)[(size_t)(i0 + i) * D + k]);
            else
                v = ((const float*)X)[(size_t)(i0 + i) * D + k];
        }
        xt[k * 68 + i] = v;
    }
    __syncthreads();
    const int tn = (t & 15) * 4;
    const int tc = (t >> 4) * 4;
    float acc[4][4] = {};
#pragma unroll 8
    for (int k = 0; k < 64; ++k) {
        const float4 xa = *(const float4*)(xt + k * 68 + tn);
        const float4 wb = *(const float4*)(wt + k * 68 + tc);
        acc[0][0] += xa.x * wb.x; acc[0][1] += xa.x * wb.y; acc[0][2] += xa.x * wb.z; acc[0][3] += xa.x * wb.w;
        acc[1][0] += xa.y * wb.x; acc[1][1] += xa.y * wb.y; acc[1][2] += xa.y * wb.z; acc[1][3] += xa.y * wb.w;
        acc[2][0] += xa.z * wb.x; acc[2][1] += xa.z * wb.y; acc[2][2] += xa.z * wb.z; acc[2][3] += xa.z * wb.w;
        acc[3][0] += xa.w * wb.x; acc[3][1] += xa.w * wb.y; acc[3][2] += xa.w * wb.z; acc[3][3] += xa.w * wb.w;
    }
#pragma unroll
    for (int a = 0; a < 4; ++a) {
        int i = i0 + tn + a;
        if (i < N) {
            union { __half2 h2[2]; uint2 u2; } pk;
            pk.h2[0].x = __float2half_rn(acc[a][0]);
            pk.h2[0].y = __float2half_rn(acc[a][1]);
            pk.h2[1].x = __float2half_rn(acc[a][2]);
            pk.h2[1].y = __float2half_rn(acc[a][3]);
            *(uint2*)(&H[(size_t)i * D + tc]) = pk.u2;
        }
    }
}

// --- fallback (round-1 fp32 atomic path) kernels ---------------------------
__global__ __launch_bounds__(256) void deg_kernel(const int* __restrict__ dst,
                                                  int* __restrict__ deg, int nE) {
    int e = blockIdx.x * 256 + threadIdx.x;
    if (e < nE) atomicAdd(&deg[dst[e]], 1);
}

__global__ __launch_bounds__(256) void dinv_kernel(const int* __restrict__ deg,
                                                   float* __restrict__ dinv, int N) {
    int i = blockIdx.x * 256 + threadIdx.x;
    if (i < N) dinv[i] = rsqrtf((float)deg[i] + 1.0f);
}

__global__ __launch_bounds__(256) void gemm_xwt(const float* __restrict__ X,
                                                const float* __restrict__ W,
                                                float* __restrict__ H, int N) {
    __shared__ float xt[64 * 68];
    __shared__ float wt[64 * 68];
    const int t = threadIdx.x;
    const int i0 = blockIdx.x * 64;
#pragma unroll
    for (int r = 0; r < 16; ++r) {
        int idx = r * 256 + t;
        int j = idx >> 6, k = idx & 63;
        wt[k * 68 + j] = W[idx];
    }
#pragma unroll
    for (int r = 0; r < 16; ++r) {
        int idx = r * 256 + t;
        int i = idx >> 6, k = idx & 63;
        float v = 0.0f;
        if (i0 + i < N) v = X[(size_t)(i0 + i) * D + k];
        xt[k * 68 + i] = v;
    }
    __syncthreads();
    const int tn = (t & 15) * 4;
    const int tc = (t >> 4) * 4;
    float acc[4][4] = {};
#pragma unroll 8
    for (int k = 0; k < 64; ++k) {
        const float4 xa = *(const float4*)(xt + k * 68 + tn);
        const float4 wb = *(const float4*)(wt + k * 68 + tc);
        acc[0][0] += xa.x * wb.x; acc[0][1] += xa.x * wb.y; acc[0][2] += xa.x * wb.z; acc[0][3] += xa.x * wb.w;
        acc[1][0] += xa.y * wb.x; acc[1][1] += xa.y * wb.y; acc[1][2] += xa.y * wb.z; acc[1][3] += xa.y * wb.w;
        acc[2][0] += xa.z * wb.x; acc[2][1] += xa.z * wb.y; acc[2][2] += xa.z * wb.z; acc[2][3] += xa.z * wb.w;
        acc[3][0] += xa.w * wb.x; acc[3][1] += xa.w * wb.y; acc[3][2] += xa.w * wb.z; acc[3][3] += xa.w * wb.w;
    }
#pragma unroll
    for (int a = 0; a < 4; ++a) {
        int i = i0 + tn + a;
        if (i < N) {
            float4 o = make_float4(acc[a][0], acc[a][1], acc[a][2], acc[a][3]);
            *(float4*)(H + (size_t)i * D + tc) = o;
        }
    }
}

__global__ __launch_bounds__(256) void init_out(const float* __restrict__ H,
                                                const float* __restrict__ dinv,
                                                const float* __restrict__ b,
                                                float* __restrict__ out, int N) {
    int idx4 = blockIdx.x * 256 + threadIdx.x;
    if (idx4 >= N * 16) return;
    int i = idx4 >> 4;
    int jc = idx4 & 15;
    float di = dinv[i];
    float s = di * di;
    float4 h4 = ((const float4*)H)[idx4];
    float4 b4 = ((const float4*)b)[jc];
    ((float4*)out)[idx4] = make_float4(b4.x + h4.x * s, b4.y + h4.y * s,
                                       b4.z + h4.z * s, b4.w + h4.w * s);
}

__global__ __launch_bounds__(256) void edge_scatter(const int* __restrict__ src,
                                                    const int* __restrict__ dst,
                                                    const float* __restrict__ dinv,
                                                    const float* __restrict__ H,
                                                    float* __restrict__ out, int nE) {
    int tid = blockIdx.x * 256 + threadIdx.x;
    int e = tid >> 4;
    if (e >= nE) return;
    int l = tid & 15;
    int s = src[e];
    int d = dst[e];
    float c = dinv[s] * dinv[d];
    float4 v = ((const float4*)H)[s * 16 + l];
    float* o = out + (size_t)d * D + l * 4;
    unsafeAtomicAdd(o + 0, v.x * c);
    unsafeAtomicAdd(o + 1, v.y * c);
    unsafeAtomicAdd(o + 2, v.z * c);
    unsafeAtomicAdd(o + 3, v.w * c);
}

static inline size_t align_up(size_t v, size_t a) { return (v + a - 1) & ~(a - 1); }

extern "C" void kernel_launch(void* const* d_in, const int* in_sizes, int n_in,
                              void* d_out, int out_size, void* d_ws, size_t ws_size,
                              hipStream_t stream) {
    const float* x  = (const float*)d_in[0];
    const int*   ei = (const int*)d_in[1];
    const float* W1 = (const float*)d_in[2];
    const float* b1 = (const float*)d_in[3];
    const float* W2 = (const float*)d_in[4];
    const float* b2 = (const float*)d_in[5];
    float* out = (float*)d_out;

    const int N  = in_sizes[0] / D;   // 100000
    const int nE = in_sizes[1] / 2;   // 1600000
    const int* srcp = ei;
    const int* dstv = ei + nE;

    const int B = (N + NPB - 1) / NPB;      // 782
    const int C = (nE + CHUNK - 1) / CHUNK; // 196

    // --- workspace layout (bump allocator, 256B aligned) ---
    char* base_p = (char*)d_ws;
    size_t o = 0;
    int* counts = (int*)(base_p + o);  o = align_up(o + (size_t)C * B * 4, 256);
    int* btot   = (int*)(base_p + o);  o = align_up(o + (size_t)B * 4, 256);
    int* bbase  = (int*)(base_p + o);  o = align_up(o + (size_t)(B + 1) * 4, 256);
    int* off    = (int*)(base_p + o);  o = align_up(o + (size_t)N * 4, 256);
    int* deg    = (int*)(base_p + o);  o = align_up(o + (size_t)N * 4, 256);
    float* dinv = (float*)(base_p + o); o = align_up(o + (size_t)N * 4, 256);
    int2* entries1 = (int2*)(base_p + o); o = align_up(o + (size_t)nE * 8, 256);
    // region2: entries0 (nE*4) while building; Hh (N*D*2) afterwards
    size_t r2 = (size_t)nE * 4 > (size_t)N * D * 2 ? (size_t)nE * 4 : (size_t)N * D * 2;
    int* entries0 = (int*)(base_p + o);
    __half* Hh    = (__half*)(base_p + o);
    o = align_up(o + r2, 256);
    size_t need_base = o;              // ~28 MB
    __half* A1h = (__half*)(base_p + o);
    size_t need_full = o + align_up((size_t)N * D * 2, 256);  // ~41 MB

    int gb_n = (N + 255) / 256;
    int gb_g = (N + 63) / 64;
    int gb_e = (nE + 255) / 256;

    if (ws_size >= need_base && B <= MAXB && B <= 1024) {
        // ---- partition build (6 dispatches, reused both layers) ----
        hist_kernel<<<C, 256, 0, stream>>>(dstv, counts, nE, B);
        scan_chunks<<<(B + 3) / 4, 256, 0, stream>>>(counts, btot, B, C);
        scan_buckets<<<1, 256, 0, stream>>>(btot, bbase, B);
        scatter0_kernel<<<C, 256, 0, stream>>>(srcp, dstv, counts, bbase, entries0, nE, B);
        regroup_count<<<B, 256, 0, stream>>>(entries0, bbase, off, deg, dinv, N);
        regroup_scatter<<<B, 256, 0, stream>>>(entries0, bbase, off, dinv, entries1, N);
        // (entries0 dead from here; its memory becomes Hh)

        int gb_a = (N + 3) / 4;
        gemm_xwt_h<float><<<gb_g, 256, 0, stream>>>(x, W1, Hh, N);
        if (ws_size >= need_full) {
            aggregate2<__half><<<gb_a, 256, 0, stream>>>(entries1, off, deg, dinv, Hh, b1, A1h, N);
            gemm_xwt_h<__half><<<gb_g, 256, 0, stream>>>(A1h, W2, Hh, N);
        } else {
            aggregate2<float><<<gb_a, 256, 0, stream>>>(entries1, off, deg, dinv, Hh, b1, out, N);
            gemm_xwt_h<float><<<gb_g, 256, 0, stream>>>(out, W2, Hh, N);
        }
        aggregate2<float><<<gb_a, 256, 0, stream>>>(entries1, off, deg, dinv, Hh, b2, out, N);
    } else {
        // ---------------- fallback: round-1 atomic path ----------------
        size_t fo = 0;
        int* fdeg    = (int*)(base_p + fo);  fo = align_up(fo + (size_t)N * 4, 256);
        float* fdinv = (float*)(base_p + fo); fo = align_up(fo + (size_t)N * 4, 256);
        float* bufA  = (float*)(base_p + fo);
        hipMemsetAsync(fdeg, 0, (size_t)N * 4, stream);
        deg_kernel<<<gb_e, 256, 0, stream>>>(dstv, fdeg, nE);
        dinv_kernel<<<gb_n, 256, 0, stream>>>(fdeg, fdinv, N);
        int gb_i = (N * 16 + 255) / 256;
        int gb_e16 = (int)(((long long)nE * 16 + 255) / 256);
        gemm_xwt<<<gb_g, 256, 0, stream>>>(x, W1, bufA, N);
        init_out<<<gb_i, 256, 0, stream>>>(bufA, fdinv, b1, out, N);
        edge_scatter<<<gb_e16, 256, 0, stream>>>(srcp, dstv, fdinv, bufA, out, nE);
        gemm_xwt<<<gb_g, 256, 0, stream>>>(out, W2, bufA, N);
        init_out<<<gb_i, 256, 0, stream>>>(bufA, fdinv, b2, out, N);
        edge_scatter<<<gb_e16, 256, 0, stream>>>(srcp, dstv, fdinv, bufA, out, nE);
    }
}

// Round 9
// 282.241 us; speedup vs baseline: 2.5368x; 1.0626x over previous
//
#include <hip/hip_runtime.h>
#include <hip/hip_fp16.h>

// ---------------------------------------------------------------------------
// 2-layer GCN. Round 9: aggregate is past-L2-traffic bound (~2.1 TB/s random
// mix; r6/r8 instruction changes were flat). Cut bytes/edge + dispatches:
//  - entries are 4B (src only); aggregate reads dinv[src] (400KB, L2-resident
//    broadcast hit) and computes norm in-kernel -> entry FETCH halves.
//  - regroup_count+regroup_scatter merged (no cross-bucket dinv dep anymore).
//  - scan_buckets folded into scan_chunks via global-cursor region alloc
//    (bucket regions unordered but contiguous -- all consumers use
//    bbase[b]/btot[b]/off[] so order is irrelevant).
// Dispatches: 8 (hist, scan_alloc, scatter0, regroup, gemm1, agg1, gemm2, agg2).
// NEVER use cooperative grid.sync on this stack (r7: ~90us/sync).
// ---------------------------------------------------------------------------

#define D 64
#define NPB 128          // nodes per bucket (dst >> 7)
#define MAXB 784         // >= ceil(100000/128) = 782
#define CHUNK 8192       // edges per partition chunk

// --- A1: per-chunk bucket histogram (LDS atomics only). Zeroes cursor. -----
__global__ __launch_bounds__(256) void hist_kernel(const int* __restrict__ dst,
                                                   int* __restrict__ counts,
                                                   int* __restrict__ cursor,
                                                   int nE, int B) {
    __shared__ int hist[MAXB];
    if (blockIdx.x == 0 && threadIdx.x == 0) *cursor = 0;  // consumed next kernel
    int c = blockIdx.x;
    for (int b = threadIdx.x; b < B; b += 256) hist[b] = 0;
    __syncthreads();
    int e0 = c * CHUNK;
#pragma unroll
    for (int i = 0; i < CHUNK / 256; ++i) {
        int e = e0 + i * 256 + threadIdx.x;
        if (e < nE) atomicAdd(&hist[dst[e] >> 7], 1);
    }
    __syncthreads();
    for (int b = threadIdx.x; b < B; b += 256) counts[c * B + b] = hist[b];
}

// --- S1: per-bucket chunk scan (in place) + region alloc via global cursor -
// One wave per bucket. Bucket regions are contiguous but globally UNORDERED.
__global__ __launch_bounds__(256) void scan_alloc(int* __restrict__ counts,
                                                  int* __restrict__ btot,
                                                  int* __restrict__ bbase,
                                                  int* __restrict__ cursor,
                                                  int B, int C) {
    int b = blockIdx.x * 4 + (threadIdx.x >> 6);
    if (b >= B) return;
    int lane = threadIdx.x & 63;
    int running = 0;
    for (int c0 = 0; c0 < C; c0 += 64) {
        int c = c0 + lane;
        int v = (c < C) ? counts[c * B + b] : 0;
        int x = v;
#pragma unroll
        for (int s = 1; s < 64; s <<= 1) {
            int u = __shfl_up(x, s);
            if (lane >= s) x += u;
        }
        if (c < C) counts[c * B + b] = running + x - v;   // exclusive in bucket
        running += __shfl(x, 63);
    }
    if (lane == 0) {
        int base = atomicAdd(cursor, running);            // order-free alloc
        bbase[b] = base;
        btot[b]  = running;
    }
}

// --- A3: scatter 4B entries (src | dloc<<17) via LDS cursors ---------------
__global__ __launch_bounds__(256) void scatter0_kernel(const int* __restrict__ src,
                                                       const int* __restrict__ dst,
                                                       const int* __restrict__ base,
                                                       const int* __restrict__ bbase,
                                                       int* __restrict__ entries0,
                                                       int nE, int B) {
    __shared__ int cur[MAXB];
    int c = blockIdx.x;
    for (int b = threadIdx.x; b < B; b += 256) cur[b] = base[c * B + b] + bbase[b];
    __syncthreads();
    int e0 = c * CHUNK;
#pragma unroll
    for (int i = 0; i < CHUNK / 256; ++i) {
        int e = e0 + i * 256 + threadIdx.x;
        if (e < nE) {
            int s = src[e], d = dst[e];
            int pos = atomicAdd(&cur[d >> 7], 1);
            entries0[pos] = s | ((d & (NPB - 1)) << 17);
        }
    }
}

// --- A4: merged regroup: count+scan -> off/deg/dinv, then node-sorted src --
// Two passes over the bucket's ~8KB segment (2nd pass L2-hot).
__global__ __launch_bounds__(256) void regroup_kernel(const int* __restrict__ entries0,
                                                      const int* __restrict__ bbase,
                                                      const int* __restrict__ btot,
                                                      int* __restrict__ off,
                                                      int* __restrict__ deg,
                                                      float* __restrict__ dinv,
                                                      int* __restrict__ entries1, int N) {
    __shared__ int cnt[NPB];
    __shared__ int scn[NPB];
    __shared__ int cur[NPB];
    int b = blockIdx.x;
    int t = threadIdx.x;
    if (t < NPB) cnt[t] = 0;
    __syncthreads();
    int s0 = bbase[b], s1 = s0 + btot[b];
    for (int p = s0 + t; p < s1; p += 256)
        atomicAdd(&cnt[(entries0[p] >> 17) & (NPB - 1)], 1);
    __syncthreads();
    if (t < NPB) scn[t] = cnt[t];
    __syncthreads();
    for (int s = 1; s < NPB; s <<= 1) {
        int u = 0;
        if (t < NPB && t >= s) u = scn[t - s];
        __syncthreads();
        if (t < NPB) scn[t] += u;
        __syncthreads();
    }
    if (t < NPB) {
        int node = b * NPB + t;
        int c = cnt[t];
        int o = s0 + scn[t] - c;       // exclusive prefix within bucket
        cur[t] = o;
        if (node < N) {
            off[node]  = o;
            deg[node]  = c;
            dinv[node] = rsqrtf((float)c + 1.0f);
        }
    }
    __syncthreads();
    for (int p = s0 + t; p < s1; p += 256) {
        int e = entries0[p];
        int pos = atomicAdd(&cur[(e >> 17) & (NPB - 1)], 1);
        entries1[pos] = e & 0x1FFFF;   // src only (4B)
    }
}

// --- aggregate3: one wave per node, dual-edge half2, 4B src entries --------
// norm computed in-kernel: dinv[src] is a 400KB L2-resident broadcast read.
template <typename OutT>
__global__ __launch_bounds__(256) void aggregate3(const int* __restrict__ csr,
                                                  const int* __restrict__ off,
                                                  const int* __restrict__ deg,
                                                  const float* __restrict__ dinv,
                                                  const __half* __restrict__ H,
                                                  const float* __restrict__ bias,
                                                  OutT* __restrict__ out, int N) {
    int node = blockIdx.x * 4 + (threadIdx.x >> 6);
    if (node >= N) return;
    int lane = threadIdx.x & 63;
    int p2 = lane & 31;
    int h  = lane >> 5;
    const __half2* H2 = (const __half2*)H;
    float dd = dinv[node];
    float2 acc = make_float2(0.0f, 0.0f);
    int beg = off[node];
    int end = beg + deg[node];
    int p = beg;
    for (; p + 16 <= end; p += 16) {       // 8 x 256B gathers in flight
        int s[8];
#pragma unroll
        for (int i = 0; i < 8; ++i) s[i] = csr[p + 2 * i + h];
        __half2 g[8];
        float dv[8];
#pragma unroll
        for (int i = 0; i < 8; ++i) {
            g[i]  = H2[(size_t)s[i] * 32 + p2];
            dv[i] = dinv[s[i]];
        }
#pragma unroll
        for (int i = 0; i < 8; ++i) {
            float2 f = __half22float2(g[i]);
            float c = dv[i] * dd;
            acc.x += f.x * c; acc.y += f.y * c;
        }
    }
    for (; p + 8 <= end; p += 8) {
        int s0v = csr[p + 0 + h], s1v = csr[p + 2 + h];
        int s2v = csr[p + 4 + h], s3v = csr[p + 6 + h];
        __half2 g0 = H2[(size_t)s0v * 32 + p2];
        __half2 g1 = H2[(size_t)s1v * 32 + p2];
        __half2 g2 = H2[(size_t)s2v * 32 + p2];
        __half2 g3 = H2[(size_t)s3v * 32 + p2];
        float c0 = dinv[s0v] * dd, c1 = dinv[s1v] * dd;
        float c2 = dinv[s2v] * dd, c3 = dinv[s3v] * dd;
        float2 f0 = __half22float2(g0), f1 = __half22float2(g1);
        float2 f2 = __half22float2(g2), f3 = __half22float2(g3);
        acc.x += f0.x * c0; acc.y += f0.y * c0;
        acc.x += f1.x * c1; acc.y += f1.y * c1;
        acc.x += f2.x * c2; acc.y += f2.y * c2;
        acc.x += f3.x * c3; acc.y += f3.y * c3;
    }
    for (; p + 2 <= end; p += 2) {
        int s0v = csr[p + h];
        __half2 g0 = H2[(size_t)s0v * 32 + p2];
        float c0 = dinv[s0v] * dd;
        float2 f0 = __half22float2(g0);
        acc.x += f0.x * c0; acc.y += f0.y * c0;
    }
    if (p < end && h == 0) {
        int s0v = csr[p];
        __half2 g0 = H2[(size_t)s0v * 32 + p2];
        float c0 = dinv[s0v] * dd;
        float2 f0 = __half22float2(g0);
        acc.x += f0.x * c0; acc.y += f0.y * c0;
    }
    acc.x += __shfl_xor(acc.x, 32);
    acc.y += __shfl_xor(acc.y, 32);
    if (h == 0) {
        float s = dd * dd;
        float2 hs = __half22float2(H2[(size_t)node * 32 + p2]);
        float2 bv = ((const float2*)bias)[p2];
        float2 o;
        o.x = acc.x + bv.x + hs.x * s;
        o.y = acc.y + bv.y + hs.y * s;
        if constexpr (sizeof(OutT) == 2) {
            ((__half2*)(out + (size_t)node * D))[p2] = __float22half2_rn(o);
        } else {
            ((float2*)(out + (size_t)node * D))[p2] = o;
        }
    }
}

// --- H(fp16) = X @ W^T : 64x64 block tile, 4x4 register tile ---------------
template <typename InT>
__global__ __launch_bounds__(256) void gemm_xwt_h(const InT* __restrict__ X,
                                                  const float* __restrict__ W,
                                                  __half* __restrict__ H, int N) {
    __shared__ float xt[64 * 68];
    __shared__ float wt[64 * 68];
    const int t = threadIdx.x;
    const int i0 = blockIdx.x * 64;
#pragma unroll
    for (int r = 0; r < 16; ++r) {
        int idx = r * 256 + t;
        int j = idx >> 6, k = idx & 63;
        wt[k * 68 + j] = W[idx];
    }
#pragma unroll
    for (int r = 0; r < 16; ++r) {
        int idx = r * 256 + t;
        int i = idx >> 6, k = idx & 63;
        float v = 0.0f;
        if (i0 + i < N) {
            if constexpr (sizeof(InT) == 2)
                v = __half2float(((const __half*)X)[(size_t)(i0 + i) * D + k]);
            else
                v = ((const float*)X)[(size_t)(i0 + i) * D + k];
        }
        xt[k * 68 + i] = v;
    }
    __syncthreads();
    const int tn = (t & 15) * 4;
    const int tc = (t >> 4) * 4;
    float acc[4][4] = {};
#pragma unroll 8
    for (int k = 0; k < 64; ++k) {
        const float4 xa = *(const float4*)(xt + k * 68 + tn);
        const float4 wb = *(const float4*)(wt + k * 68 + tc);
        acc[0][0] += xa.x * wb.x; acc[0][1] += xa.x * wb.y; acc[0][2] += xa.x * wb.z; acc[0][3] += xa.x * wb.w;
        acc[1][0] += xa.y * wb.x; acc[1][1] += xa.y * wb.y; acc[1][2] += xa.y * wb.z; acc[1][3] += xa.y * wb.w;
        acc[2][0] += xa.z * wb.x; acc[2][1] += xa.z * wb.y; acc[2][2] += xa.z * wb.z; acc[2][3] += xa.z * wb.w;
        acc[3][0] += xa.w * wb.x; acc[3][1] += xa.w * wb.y; acc[3][2] += xa.w * wb.z; acc[3][3] += xa.w * wb.w;
    }
#pragma unroll
    for (int a = 0; a < 4; ++a) {
        int i = i0 + tn + a;
        if (i < N) {
            union { __half2 h2[2]; uint2 u2; } pk;
            pk.h2[0].x = __float2half_rn(acc[a][0]);
            pk.h2[0].y = __float2half_rn(acc[a][1]);
            pk.h2[1].x = __float2half_rn(acc[a][2]);
            pk.h2[1].y = __float2half_rn(acc[a][3]);
            *(uint2*)(&H[(size_t)i * D + tc]) = pk.u2;
        }
    }
}

// --- fallback (round-1 fp32 atomic path) kernels ---------------------------
__global__ __launch_bounds__(256) void deg_kernel(const int* __restrict__ dst,
                                                  int* __restrict__ deg, int nE) {
    int e = blockIdx.x * 256 + threadIdx.x;
    if (e < nE) atomicAdd(&deg[dst[e]], 1);
}

__global__ __launch_bounds__(256) void dinv_kernel(const int* __restrict__ deg,
                                                   float* __restrict__ dinv, int N) {
    int i = blockIdx.x * 256 + threadIdx.x;
    if (i < N) dinv[i] = rsqrtf((float)deg[i] + 1.0f);
}

__global__ __launch_bounds__(256) void gemm_xwt(const float* __restrict__ X,
                                                const float* __restrict__ W,
                                                float* __restrict__ H, int N) {
    __shared__ float xt[64 * 68];
    __shared__ float wt[64 * 68];
    const int t = threadIdx.x;
    const int i0 = blockIdx.x * 64;
#pragma unroll
    for (int r = 0; r < 16; ++r) {
        int idx = r * 256 + t;
        int j = idx >> 6, k = idx & 63;
        wt[k * 68 + j] = W[idx];
    }
#pragma unroll
    for (int r = 0; r < 16; ++r) {
        int idx = r * 256 + t;
        int i = idx >> 6, k = idx & 63;
        float v = 0.0f;
        if (i0 + i < N) v = X[(size_t)(i0 + i) * D + k];
        xt[k * 68 + i] = v;
    }
    __syncthreads();
    const int tn = (t & 15) * 4;
    const int tc = (t >> 4) * 4;
    float acc[4][4] = {};
#pragma unroll 8
    for (int k = 0; k < 64; ++k) {
        const float4 xa = *(const float4*)(xt + k * 68 + tn);
        const float4 wb = *(const float4*)(wt + k * 68 + tc);
        acc[0][0] += xa.x * wb.x; acc[0][1] += xa.x * wb.y; acc[0][2] += xa.x * wb.z; acc[0][3] += xa.x * wb.w;
        acc[1][0] += xa.y * wb.x; acc[1][1] += xa.y * wb.y; acc[1][2] += xa.y * wb.z; acc[1][3] += xa.y * wb.w;
        acc[2][0] += xa.z * wb.x; acc[2][1] += xa.z * wb.y; acc[2][2] += xa.z * wb.z; acc[2][3] += xa.z * wb.w;
        acc[3][0] += xa.w * wb.x; acc[3][1] += xa.w * wb.y; acc[3][2] += xa.w * wb.z; acc[3][3] += xa.w * wb.w;
    }
#pragma unroll
    for (int a = 0; a < 4; ++a) {
        int i = i0 + tn + a;
        if (i < N) {
            float4 o = make_float4(acc[a][0], acc[a][1], acc[a][2], acc[a][3]);
            *(float4*)(H + (size_t)i * D + tc) = o;
        }
    }
}

__global__ __launch_bounds__(256) void init_out(const float* __restrict__ H,
                                                const float* __restrict__ dinv,
                                                const float* __restrict__ b,
                                                float* __restrict__ out, int N) {
    int idx4 = blockIdx.x * 256 + threadIdx.x;
    if (idx4 >= N * 16) return;
    int i = idx4 >> 4;
    int jc = idx4 & 15;
    float di = dinv[i];
    float s = di * di;
    float4 h4 = ((const float4*)H)[idx4];
    float4 b4 = ((const float4*)b)[jc];
    ((float4*)out)[idx4] = make_float4(b4.x + h4.x * s, b4.y + h4.y * s,
                                       b4.z + h4.z * s, b4.w + h4.w * s);
}

__global__ __launch_bounds__(256) void edge_scatter(const int* __restrict__ src,
                                                    const int* __restrict__ dst,
                                                    const float* __restrict__ dinv,
                                                    const float* __restrict__ H,
                                                    float* __restrict__ out, int nE) {
    int tid = blockIdx.x * 256 + threadIdx.x;
    int e = tid >> 4;
    if (e >= nE) return;
    int l = tid & 15;
    int s = src[e];
    int d = dst[e];
    float c = dinv[s] * dinv[d];
    float4 v = ((const float4*)H)[s * 16 + l];
    float* o = out + (size_t)d * D + l * 4;
    unsafeAtomicAdd(o + 0, v.x * c);
    unsafeAtomicAdd(o + 1, v.y * c);
    unsafeAtomicAdd(o + 2, v.z * c);
    unsafeAtomicAdd(o + 3, v.w * c);
}

static inline size_t align_up(size_t v, size_t a) { return (v + a - 1) & ~(a - 1); }

extern "C" void kernel_launch(void* const* d_in, const int* in_sizes, int n_in,
                              void* d_out, int out_size, void* d_ws, size_t ws_size,
                              hipStream_t stream) {
    const float* x  = (const float*)d_in[0];
    const int*   ei = (const int*)d_in[1];
    const float* W1 = (const float*)d_in[2];
    const float* b1 = (const float*)d_in[3];
    const float* W2 = (const float*)d_in[4];
    const float* b2 = (const float*)d_in[5];
    float* out = (float*)d_out;

    const int N  = in_sizes[0] / D;   // 100000
    const int nE = in_sizes[1] / 2;   // 1600000
    const int* srcp = ei;
    const int* dstv = ei + nE;

    const int B = (N + NPB - 1) / NPB;      // 782
    const int C = (nE + CHUNK - 1) / CHUNK; // 196

    // --- workspace layout (bump allocator, 256B aligned) ---
    char* base_p = (char*)d_ws;
    size_t o = 0;
    int* counts = (int*)(base_p + o);  o = align_up(o + (size_t)C * B * 4, 256);
    int* btot   = (int*)(base_p + o);  o = align_up(o + (size_t)B * 4, 256);
    int* bbase  = (int*)(base_p + o);  o = align_up(o + (size_t)B * 4, 256);
    int* cursor = (int*)(base_p + o);  o = align_up(o + 4, 256);
    int* off    = (int*)(base_p + o);  o = align_up(o + (size_t)N * 4, 256);
    int* deg    = (int*)(base_p + o);  o = align_up(o + (size_t)N * 4, 256);
    float* dinv = (float*)(base_p + o); o = align_up(o + (size_t)N * 4, 256);
    int* entries1 = (int*)(base_p + o); o = align_up(o + (size_t)nE * 4, 256);
    // region2: entries0 (nE*4) while building; Hh (N*D*2) afterwards
    size_t r2 = (size_t)nE * 4 > (size_t)N * D * 2 ? (size_t)nE * 4 : (size_t)N * D * 2;
    int* entries0 = (int*)(base_p + o);
    __half* Hh    = (__half*)(base_p + o);
    o = align_up(o + r2, 256);
    size_t need_base = o;              // ~22 MB
    __half* A1h = (__half*)(base_p + o);
    size_t need_full = o + align_up((size_t)N * D * 2, 256);  // ~35 MB

    int gb_n = (N + 255) / 256;
    int gb_g = (N + 63) / 64;
    int gb_e = (nE + 255) / 256;

    if (ws_size >= need_base && B <= MAXB) {
        // ---- partition build (4 dispatches, reused both layers) ----
        hist_kernel<<<C, 256, 0, stream>>>(dstv, counts, cursor, nE, B);
        scan_alloc<<<(B + 3) / 4, 256, 0, stream>>>(counts, btot, bbase, cursor, B, C);
        scatter0_kernel<<<C, 256, 0, stream>>>(srcp, dstv, counts, bbase, entries0, nE, B);
        regroup_kernel<<<B, 256, 0, stream>>>(entries0, bbase, btot, off, deg, dinv, entries1, N);
        // (entries0 dead from here; its memory becomes Hh)

        int gb_a = (N + 3) / 4;
        gemm_xwt_h<float><<<gb_g, 256, 0, stream>>>(x, W1, Hh, N);
        if (ws_size >= need_full) {
            aggregate3<__half><<<gb_a, 256, 0, stream>>>(entries1, off, deg, dinv, Hh, b1, A1h, N);
            gemm_xwt_h<__half><<<gb_g, 256, 0, stream>>>(A1h, W2, Hh, N);
        } else {
            aggregate3<float><<<gb_a, 256, 0, stream>>>(entries1, off, deg, dinv, Hh, b1, out, N);
            gemm_xwt_h<float><<<gb_g, 256, 0, stream>>>(out, W2, Hh, N);
        }
        aggregate3<float><<<gb_a, 256, 0, stream>>>(entries1, off, deg, dinv, Hh, b2, out, N);
    } else {
        // ---------------- fallback: round-1 atomic path ----------------
        size_t fo = 0;
        int* fdeg    = (int*)(base_p + fo);  fo = align_up(fo + (size_t)N * 4, 256);
        float* fdinv = (float*)(base_p + fo); fo = align_up(fo + (size_t)N * 4, 256);
        float* bufA  = (float*)(base_p + fo);
        hipMemsetAsync(fdeg, 0, (size_t)N * 4, stream);
        deg_kernel<<<gb_e, 256, 0, stream>>>(dstv, fdeg, nE);
        dinv_kernel<<<gb_n, 256, 0, stream>>>(fdeg, fdinv, N);
        int gb_i = (N * 16 + 255) / 256;
        int gb_e16 = (int)(((long long)nE * 16 + 255) / 256);
        gemm_xwt<<<gb_g, 256, 0, stream>>>(x, W1, bufA, N);
        init_out<<<gb_i, 256, 0, stream>>>(bufA, fdinv, b1, out, N);
        edge_scatter<<<gb_e16, 256, 0, stream>>>(srcp, dstv, fdinv, bufA, out, nE);
        gemm_xwt<<<gb_g, 256, 0, stream>>>(out, W2, bufA, N);
        init_out<<<gb_i, 256, 0, stream>>>(bufA, fdinv, b2, out, N);
        edge_scatter<<<gb_e16, 256, 0, stream>>>(srcp, dstv, fdinv, bufA, out, nE);
    }
}